// Round 22
// baseline (69.301 us; speedup 1.0000x reference)
//
#include <hip/hip_runtime.h>
#include <hip/hip_bf16.h>

// Problem constants (from reference setup_inputs)
#define RR 3
#define BB 2
#define NN 2048
#define DD 128
#define HH 4
#define HD 32
#define LEAKY 0.2f
#define LN_EPS 1e-5f
#define LOG2E 1.4426950408889634f

using f32x4  = __attribute__((ext_vector_type(4))) float;
using bf16x8 = __attribute__((ext_vector_type(8))) short;

__device__ __forceinline__ unsigned short bfb(float x) {
    return __builtin_bit_cast(unsigned short, __float2bfloat16(x));
}

// ---------------------------------------------------------------------------
// Layouts (proven correct R20/R21):
//  whT tiled: [rbh][S 0..15][jc 4][kg 4][f 32][e 8] bf16.
//  bm transposed: [rb 6][wordidx 0..63][nrow 0..2047] u32; word (e,q,h):
//    bit i <-> j = e*256 + h*128 + 4i + q; wordidx = e*8 + q*2 + h.
// Factorized softmax: p = exp2(max(uA+ev, 0.2ev+vA))
//                       = max(exp2(uA)*E1[j], exp2(vA)*E2[j])
//   with E1 = exp2(ev), E2 = exp2(0.2*ev) precomputed in prep.
// ---------------------------------------------------------------------------

// ---------------------------------------------------------------------------
// Kernel 1: fused prep. grid = 768 compact + 384 wh = 1152 blocks.
// wh role now also writes E1/E2 (exp2 of log2e-scaled ed and 0.2*ed).
// ---------------------------------------------------------------------------
__global__ __launch_bounds__(256) void prep_kernel(
    const float* __restrict__ H, const int* __restrict__ A,
    const float* __restrict__ W,
    const float* __restrict__ a_src, const float* __restrict__ a_dst,
    float* __restrict__ es, float* __restrict__ ed,
    float* __restrict__ E1, float* __restrict__ E2,
    __hip_bfloat16* __restrict__ whT, unsigned* __restrict__ bm)
{
    __shared__ unsigned cb_lds[16][65];   // padded transpose buffer

    const int bid = blockIdx.x;
    const int t = threadIdx.x;
    const int w = t >> 6;
    const int l = t & 63;

    if (bid < 768) {
        // ---- compact role: 16 rows, ballot -> LDS transpose -> lines ----
        const int sel_e = l >> 3;
        const int sel_q = (l >> 1) & 3;
        const int sel_h = l & 1;
#pragma unroll
        for (int iter = 0; iter < 4; ++iter) {
            const int lr = iter * 4 + w;
            const long crow = (long)bid * 16 + lr;
            const int4* Ap = (const int4*)A + crow * 512 + l;
            int4 v[8];
#pragma unroll
            for (int e = 0; e < 8; ++e) v[e] = Ap[e * 64];
            unsigned word = 0;
#pragma unroll
            for (int e = 0; e < 8; ++e) {
                const unsigned long long B0 = __ballot(v[e].x != 0);
                const unsigned long long B1 = __ballot(v[e].y != 0);
                const unsigned long long B2 = __ballot(v[e].z != 0);
                const unsigned long long B3 = __ballot(v[e].w != 0);
                if (sel_e == e) {
                    const unsigned long long Bq =
                        (sel_q == 3) ? B3 : (sel_q == 2) ? B2 : (sel_q == 1) ? B1 : B0;
                    word = sel_h ? (unsigned)(Bq >> 32) : (unsigned)Bq;
                }
            }
            cb_lds[lr][l] = word;
        }
        __syncthreads();
        {
            const long nrow0g = (long)bid * 16;
            const int rb = (int)(nrow0g >> 11);
            const int nrow0 = (int)(nrow0g & 2047);
            const int p = t >> 2, c = t & 3;
            uint4 val;
            val.x = cb_lds[c * 4 + 0][p];
            val.y = cb_lds[c * 4 + 1][p];
            val.z = cb_lds[c * 4 + 2][p];
            val.w = cb_lds[c * 4 + 3][p];
            *(uint4*)(bm + ((long)rb * 64 + p) * 2048 + nrow0 + c * 4) = val;
        }
        return;
    }

    // ---- wh role ----
    const int wb = bid - 768;
    const int rbh = wb >> 4;
    const int nch = wb & 15;
    const int h = rbh & 3;
    const int b = (rbh >> 2) & 1;
    const int r = rbh >> 3;
    const int wi = r * HH + h;
    const int lr = l & 15;
    const int lg = l >> 4;

    const float* Wp = W + (long)wi * DD * HD;
    bf16x8 afr[2][4];
#pragma unroll
    for (int mt = 0; mt < 2; ++mt)
#pragma unroll
        for (int kt = 0; kt < 4; ++kt)
#pragma unroll
            for (int e = 0; e < 8; ++e)
                afr[mt][kt][e] = (short)bfb(Wp[(kt * 32 + lg * 8 + e) * HD + mt * 16 + lr]);

    float av[2][4], dv[2][4];
#pragma unroll
    for (int mt = 0; mt < 2; ++mt)
#pragma unroll
        for (int reg = 0; reg < 4; ++reg) {
            const int f = mt * 16 + lg * 4 + reg;
            av[mt][reg] = a_src[wi * HD + f] * LOG2E;
            dv[mt][reg] = a_dst[wi * HD + f] * LOG2E;
        }

    __hip_bfloat16* tile = whT + ((long)rbh * 16 + nch) * 4096;

#pragma unroll
    for (int nt = 0; nt < 2; ++nt) {
        const int ncol = nch * 128 + w * 32 + nt * 16 + lr;
        const float4* hrow4 = (const float4*)(H + ((long)b * NN + ncol) * DD);
        f32x4 acc0 = {0.f, 0.f, 0.f, 0.f};
        f32x4 acc1 = {0.f, 0.f, 0.f, 0.f};
#pragma unroll
        for (int kt = 0; kt < 4; ++kt) {
            float4 h0 = hrow4[kt * 8 + lg * 2];
            float4 h1 = hrow4[kt * 8 + lg * 2 + 1];
            bf16x8 bfr;
            bfr[0] = (short)bfb(h0.x); bfr[1] = (short)bfb(h0.y);
            bfr[2] = (short)bfb(h0.z); bfr[3] = (short)bfb(h0.w);
            bfr[4] = (short)bfb(h1.x); bfr[5] = (short)bfb(h1.y);
            bfr[6] = (short)bfb(h1.z); bfr[7] = (short)bfb(h1.w);
            acc0 = __builtin_amdgcn_mfma_f32_16x16x32_bf16(afr[0][kt], bfr, acc0, 0, 0, 0);
            acc1 = __builtin_amdgcn_mfma_f32_16x16x32_bf16(afr[1][kt], bfr, acc1, 0, 0, 0);
        }
        const int kgw = nt * 2 + (lr >> 3);
        const int ew = lr & 7;
        float s = 0.f, d = 0.f;
#pragma unroll
        for (int reg = 0; reg < 4; ++reg) {
            const int f0 = lg * 4 + reg;
            const int f1 = 16 + lg * 4 + reg;
            tile[((w * 4 + kgw) * 32 + f0) * 8 + ew] = __float2bfloat16(acc0[reg]);
            tile[((w * 4 + kgw) * 32 + f1) * 8 + ew] = __float2bfloat16(acc1[reg]);
            s = fmaf(acc0[reg], av[0][reg], s);
            s = fmaf(acc1[reg], av[1][reg], s);
            d = fmaf(acc0[reg], dv[0][reg], d);
            d = fmaf(acc1[reg], dv[1][reg], d);
        }
        s += __shfl_xor(s, 16); s += __shfl_xor(s, 32);
        d += __shfl_xor(d, 16); d += __shfl_xor(d, 32);
        if (l < 16) {
            es[(long)rbh * NN + ncol] = s;
            ed[(long)rbh * NN + ncol] = d;
            E1[(long)rbh * NN + ncol] = __builtin_amdgcn_exp2f(d);
            E2[(long)rbh * NN + ncol] = __builtin_amdgcn_exp2f(LEAKY * d);
        }
    }
}

// ---------------------------------------------------------------------------
// Kernel 2: BARRIER-FREE gat with FACTORIZED softmax. No LDS, no barriers,
// no setprio (m190: hurts lockstep-free loops too). Per element:
// p = max(PA*E1[j], PB*E2[j]) -> mask-AND -> truncating v_perm pack.
// grid = R*B*128*2 = 1536 blocks (XCD swizzled), 24 waves/CU.
// ---------------------------------------------------------------------------
__global__ __launch_bounds__(256, 6) void gat_attn_kernel(
    const unsigned* __restrict__ bm, const float* __restrict__ es,
    const float* __restrict__ ed, const float* __restrict__ E1,
    const float* __restrict__ E2, const __hip_bfloat16* __restrict__ whT,
    unsigned* __restrict__ num, float* __restrict__ den)
{
    const int lg = ((int)blockIdx.x % 8) * 192 + (int)blockIdx.x / 8;
    const int jh = lg & 1;
    const int it = (lg >> 1) & 127;        // 16-row i-tile
    const int b  = (lg >> 8) & 1;
    const int r  = lg >> 9;
    const int i0 = it << 4;
    const int tid = threadIdx.x;
    const int h = tid >> 6;                // wave = head
    const int l = tid & 63;
    const int row = l & 15;
    const int kg  = l >> 4;

    const int rb  = r * BB + b;
    const int rbh = rb * HH + h;
    const float* edr = ed + (long)rbh * NN;

    // per-wave max of ed over all 2048 j (upper bound; cancels in num/den)
    float mm = -1e30f;
#pragma unroll
    for (int k = 0; k < 8; ++k) {
        float4 v = ((const float4*)edr)[k * 64 + l];
        mm = fmaxf(mm, fmaxf(fmaxf(v.x, v.y), fmaxf(v.z, v.w)));
    }
#pragma unroll
    for (int d = 1; d < 64; d <<= 1) mm = fmaxf(mm, __shfl_xor(mm, d));

    const float esv = es[(long)rbh * NN + i0 + row];   // log2e-scaled
    const float x = esv + mm;
    const float M = fmaxf(x, LEAKY * x);
    const float PA = __builtin_amdgcn_exp2f(esv - M);
    const float PB = __builtin_amdgcn_exp2f(fmaf(LEAKY, esv, -M));

    f32x4 acc0 = {0,0,0,0}, acc1 = {0,0,0,0}, accD = {0,0,0,0};
    bf16x8 ones;
#pragma unroll
    for (int i = 0; i < 8; ++i) ones[i] = (short)0x3F80;

    const int kk = kg * 2;
    const unsigned* bmb = bm + (long)rb * 64 * 2048 + i0 + row;
    const float* E1r = E1 + (long)rbh * NN;
    const float* E2r = E2 + (long)rbh * NN;

#pragma unroll 2
    for (int seg = 0; seg < 8; ++seg) {
        const int S = jh * 8 + seg;
        const __hip_bfloat16* tile = whT + ((long)rbh * 16 + S) * 4096;
        const int wbase = (S >> 1) * 8 + (S & 1);
        unsigned wA[4];
#pragma unroll
        for (int q = 0; q < 4; ++q)
            wA[q] = bmb[(long)(wbase + q * 2) * 2048];
        const float* e1seg = E1r + S * 128;
        const float* e2seg = E2r + S * 128;

#pragma unroll
        for (int jc = 0; jc < 4; ++jc) {
            bf16x8 b0 = *(const bf16x8*)(tile + jc * 1024 + kg * 256 + row * 8);
            bf16x8 b1 = *(const bf16x8*)(tile + jc * 1024 + kg * 256 + 128 + row * 8);
            float4 a0 = *(const float4*)(e1seg + jc * 32 + kg * 8);
            float4 a1 = *(const float4*)(e1seg + jc * 32 + kg * 8 + 4);
            float4 c0 = *(const float4*)(e2seg + jc * 32 + kg * 8);
            float4 c1 = *(const float4*)(e2seg + jc * 32 + kg * 8 + 4);

            unsigned uq[4];
#pragma unroll
            for (int q = 0; q < 4; ++q) uq[q] = wA[q] >> (jc * 8 + kk);

            float e1v[8], e2v[8];
            e1v[0] = a0.x; e1v[1] = a0.y; e1v[2] = a0.z; e1v[3] = a0.w;
            e1v[4] = a1.x; e1v[5] = a1.y; e1v[6] = a1.z; e1v[7] = a1.w;
            e2v[0] = c0.x; e2v[1] = c0.y; e2v[2] = c0.z; e2v[3] = c0.w;
            e2v[4] = c1.x; e2v[5] = c1.y; e2v[6] = c1.z; e2v[7] = c1.w;

            unsigned pw[4];
#pragma unroll
            for (int k2 = 0; k2 < 4; ++k2) {
                unsigned pb[2];
#pragma unroll
                for (int sub = 0; sub < 2; ++sub) {
                    const int c = k2 * 2 + sub;
                    float p = fmaxf(PA * e1v[c], PB * e2v[c]);
                    const int ma = ((int)(uq[c & 3] << (31 - (c >> 2)))) >> 31;
                    pb[sub] = __float_as_uint(p) & (unsigned)ma;
                }
                // [bf16(p0) | bf16(p1)<<16] via byte-perm (truncating)
                pw[k2] = __builtin_amdgcn_perm(pb[1], pb[0], 0x07060302u);
            }
            union { unsigned u[4]; bf16x8 v; } pk;
            pk.u[0] = pw[0]; pk.u[1] = pw[1]; pk.u[2] = pw[2]; pk.u[3] = pw[3];

            acc0 = __builtin_amdgcn_mfma_f32_16x16x32_bf16(pk.v, b0, acc0, 0, 0, 0);
            acc1 = __builtin_amdgcn_mfma_f32_16x16x32_bf16(pk.v, b1, acc1, 0, 0, 0);
            accD = __builtin_amdgcn_mfma_f32_16x16x32_bf16(pk.v, ones, accD, 0, 0, 0);
        }
    }

    // epilogue: packed bf16 numerators + fp32 denominators
    const int fcol = l & 15;
    const int pr = r * 2 + jh;
#pragma unroll
    for (int reg = 0; reg < 4; ++reg) {
        const int orow = (l >> 4) * 4 + reg;
        const long ro = (long)pr * (BB * NN) + (long)b * NN + i0 + orow;
        num[ro * 64 + h * 16 + fcol] =
            (unsigned)bfb(acc0[reg]) | ((unsigned)bfb(acc1[reg]) << 16);
        if (fcol == 0) den[ro * HH + h] = accD[reg];
    }
}

// ---------------------------------------------------------------------------
// Kernel 3: out = LayerNorm(H + mean_r (num_r / den_r)); 2 j-chunks.
// ---------------------------------------------------------------------------
__global__ __launch_bounds__(256) void finalize_kernel(
    const float* __restrict__ H, const unsigned* __restrict__ num,
    const float* __restrict__ den,
    const float* __restrict__ gamma, const float* __restrict__ beta,
    float* __restrict__ out)
{
    const int w = threadIdx.x >> 6;
    const int l = threadIdx.x & 63;
    const long row = (long)blockIdx.x * 4 + w;
    const int hh = l >> 4, cc = l & 15;
    const int c_lo = hh * 32 + cc, c_hi = c_lo + 16;
    const float hx = H[row * DD + c_lo];
    const float hy = H[row * DD + c_hi];

    float ax = 0.f, ay = 0.f;
#pragma unroll
    for (int r = 0; r < RR; ++r) {
        float dsum = 0.f, nx = 0.f, ny = 0.f;
#pragma unroll
        for (int j = 0; j < 2; ++j) {
            const long ro = (long)(r * 2 + j) * (BB * NN) + row;
            dsum += den[ro * HH + hh];
            const unsigned wv = num[ro * 64 + l];
            nx += __uint_as_float(wv << 16);
            ny += __uint_as_float(wv & 0xffff0000u);
        }
        const float inv = (dsum > 0.f) ? 1.0f / dsum : 0.0f;
        ax = fmaf(nx, inv, ax);
        ay = fmaf(ny, inv, ay);
    }
    const float x0 = hx + ax * (1.0f / RR);
    const float x1 = hy + ay * (1.0f / RR);
    float s = x0 + x1, q = x0 * x0 + x1 * x1;
#pragma unroll
    for (int m = 1; m < 64; m <<= 1) {
        s += __shfl_xor(s, m);
        q += __shfl_xor(q, m);
    }
    const float mu  = s * (1.0f / DD);
    const float var = q * (1.0f / DD) - mu * mu;
    const float inv = rsqrtf(var + LN_EPS);
    out[row * DD + c_lo] = (x0 - mu) * inv * gamma[c_lo] + beta[c_lo];
    out[row * DD + c_hi] = (x1 - mu) * inv * gamma[c_hi] + beta[c_hi];
}

// ---------------------------------------------------------------------------
extern "C" void kernel_launch(void* const* d_in, const int* in_sizes, int n_in,
                              void* d_out, int out_size, void* d_ws, size_t ws_size,
                              hipStream_t stream)
{
    const float* H      = (const float*)d_in[0];
    const int*   A      = (const int*)d_in[1];
    const float* W      = (const float*)d_in[2];
    const float* a_src  = (const float*)d_in[3];
    const float* a_dst  = (const float*)d_in[4];
    const float* gamma  = (const float*)d_in[5];
    const float* beta   = (const float*)d_in[6];
    float* out = (float*)d_out;

    // workspace carve (~13.8 MB)
    char* ws = (char*)d_ws;
    unsigned* num = (unsigned*)ws;               ws += (size_t)RR * 2 * BB * NN * 64 * 4;
    float* den = (float*)ws;                     ws += (size_t)RR * 2 * BB * NN * HH * 4;
    float* es  = (float*)ws;                     ws += (size_t)RR * BB * HH * NN * 4;
    float* ed  = (float*)ws;                     ws += (size_t)RR * BB * HH * NN * 4;
    float* E1  = (float*)ws;                     ws += (size_t)RR * BB * HH * NN * 4;
    float* E2  = (float*)ws;                     ws += (size_t)RR * BB * HH * NN * 4;
    __hip_bfloat16* whT = (__hip_bfloat16*)ws;   ws += (size_t)RR * BB * HH * HD * NN * 2;
    unsigned* bmask = (unsigned*)ws;             ws += (size_t)RR * BB * NN * (NN / 32) * 4;

    prep_kernel<<<768 + 384, 256, 0, stream>>>(
        H, A, W, a_src, a_dst, es, ed, E1, E2, whT, bmask);
    gat_attn_kernel<<<RR * BB * 128 * 2, 256, 0, stream>>>(
        bmask, es, ed, E1, E2, whT, num, den);
    finalize_kernel<<<BB * NN / 4, 256, 0, stream>>>(H, num, den, gamma, beta, out);
}

// Round 23
// 63.141 us; speedup vs baseline: 1.0976x; 1.0976x over previous
//
#include <hip/hip_runtime.h>
#include <hip/hip_bf16.h>

// Problem constants (from reference setup_inputs)
#define RR 3
#define BB 2
#define NN 2048
#define DD 128
#define HH 4
#define HD 32
#define LEAKY 0.2f
#define LN_EPS 1e-5f
#define LOG2E 1.4426950408889634f

using f32x4  = __attribute__((ext_vector_type(4))) float;
using bf16x8 = __attribute__((ext_vector_type(8))) short;

__device__ __forceinline__ unsigned short bfb(float x) {
    return __builtin_bit_cast(unsigned short, __float2bfloat16(x));
}

// ---------------------------------------------------------------------------
// Layouts (proven correct R20/R21):
//  whT tiled: [rbh][S 0..15][jc 4][kg 4][f 32][e 8] bf16 — 8KB per 128-j
//    segment; b0/b1 fragment reads are fully dense 1KB wave-loads.
//  bm transposed: [rb 6][wordidx 0..63][nrow 0..2047] u32; word (e,q,h):
//    bit i <-> j = e*256 + h*128 + 4i + q; wordidx = e*8 + q*2 + h.
//    Mask bit for col c of jc: bit (c>>2) of (word[c&3] >> (jc*8 + kg*2)).
// ---------------------------------------------------------------------------

// ---------------------------------------------------------------------------
// Kernel 1: fused prep. grid = 768 compact + 384 wh = 1152 blocks.
// ---------------------------------------------------------------------------
__global__ __launch_bounds__(256) void prep_kernel(
    const float* __restrict__ H, const int* __restrict__ A,
    const float* __restrict__ W,
    const float* __restrict__ a_src, const float* __restrict__ a_dst,
    float* __restrict__ es, float* __restrict__ ed,
    __hip_bfloat16* __restrict__ whT, unsigned* __restrict__ bm)
{
    __shared__ unsigned cb_lds[16][65];   // padded transpose buffer

    const int bid = blockIdx.x;
    const int t = threadIdx.x;
    const int w = t >> 6;
    const int l = t & 63;

    if (bid < 768) {
        // ---- compact role: 16 rows, ballot -> LDS transpose -> lines ----
        const int sel_e = l >> 3;
        const int sel_q = (l >> 1) & 3;
        const int sel_h = l & 1;
#pragma unroll
        for (int iter = 0; iter < 4; ++iter) {
            const int lr = iter * 4 + w;
            const long crow = (long)bid * 16 + lr;
            const int4* Ap = (const int4*)A + crow * 512 + l;
            int4 v[8];
#pragma unroll
            for (int e = 0; e < 8; ++e) v[e] = Ap[e * 64];
            unsigned word = 0;
#pragma unroll
            for (int e = 0; e < 8; ++e) {
                const unsigned long long B0 = __ballot(v[e].x != 0);
                const unsigned long long B1 = __ballot(v[e].y != 0);
                const unsigned long long B2 = __ballot(v[e].z != 0);
                const unsigned long long B3 = __ballot(v[e].w != 0);
                if (sel_e == e) {
                    const unsigned long long Bq =
                        (sel_q == 3) ? B3 : (sel_q == 2) ? B2 : (sel_q == 1) ? B1 : B0;
                    word = sel_h ? (unsigned)(Bq >> 32) : (unsigned)Bq;
                }
            }
            cb_lds[lr][l] = word;
        }
        __syncthreads();
        {
            const long nrow0g = (long)bid * 16;
            const int rb = (int)(nrow0g >> 11);
            const int nrow0 = (int)(nrow0g & 2047);
            const int p = t >> 2, c = t & 3;
            uint4 val;
            val.x = cb_lds[c * 4 + 0][p];
            val.y = cb_lds[c * 4 + 1][p];
            val.z = cb_lds[c * 4 + 2][p];
            val.w = cb_lds[c * 4 + 3][p];
            *(uint4*)(bm + ((long)rb * 64 + p) * 2048 + nrow0 + c * 4) = val;
        }
        return;
    }

    // ---- wh role ----
    const int wb = bid - 768;
    const int rbh = wb >> 4;
    const int nch = wb & 15;
    const int h = rbh & 3;
    const int b = (rbh >> 2) & 1;
    const int r = rbh >> 3;
    const int wi = r * HH + h;
    const int lr = l & 15;
    const int lg = l >> 4;

    const float* Wp = W + (long)wi * DD * HD;
    bf16x8 afr[2][4];
#pragma unroll
    for (int mt = 0; mt < 2; ++mt)
#pragma unroll
        for (int kt = 0; kt < 4; ++kt)
#pragma unroll
            for (int e = 0; e < 8; ++e)
                afr[mt][kt][e] = (short)bfb(Wp[(kt * 32 + lg * 8 + e) * HD + mt * 16 + lr]);

    float av[2][4], dv[2][4];
#pragma unroll
    for (int mt = 0; mt < 2; ++mt)
#pragma unroll
        for (int reg = 0; reg < 4; ++reg) {
            const int f = mt * 16 + lg * 4 + reg;
            av[mt][reg] = a_src[wi * HD + f] * LOG2E;
            dv[mt][reg] = a_dst[wi * HD + f] * LOG2E;
        }

    __hip_bfloat16* tile = whT + ((long)rbh * 16 + nch) * 4096;

#pragma unroll
    for (int nt = 0; nt < 2; ++nt) {
        const int ncol = nch * 128 + w * 32 + nt * 16 + lr;
        const float4* hrow4 = (const float4*)(H + ((long)b * NN + ncol) * DD);
        f32x4 acc0 = {0.f, 0.f, 0.f, 0.f};
        f32x4 acc1 = {0.f, 0.f, 0.f, 0.f};
#pragma unroll
        for (int kt = 0; kt < 4; ++kt) {
            float4 h0 = hrow4[kt * 8 + lg * 2];
            float4 h1 = hrow4[kt * 8 + lg * 2 + 1];
            bf16x8 bfr;
            bfr[0] = (short)bfb(h0.x); bfr[1] = (short)bfb(h0.y);
            bfr[2] = (short)bfb(h0.z); bfr[3] = (short)bfb(h0.w);
            bfr[4] = (short)bfb(h1.x); bfr[5] = (short)bfb(h1.y);
            bfr[6] = (short)bfb(h1.z); bfr[7] = (short)bfb(h1.w);
            acc0 = __builtin_amdgcn_mfma_f32_16x16x32_bf16(afr[0][kt], bfr, acc0, 0, 0, 0);
            acc1 = __builtin_amdgcn_mfma_f32_16x16x32_bf16(afr[1][kt], bfr, acc1, 0, 0, 0);
        }
        const int kgw = nt * 2 + (lr >> 3);
        const int ew = lr & 7;
        float s = 0.f, d = 0.f;
#pragma unroll
        for (int reg = 0; reg < 4; ++reg) {
            const int f0 = lg * 4 + reg;
            const int f1 = 16 + lg * 4 + reg;
            tile[((w * 4 + kgw) * 32 + f0) * 8 + ew] = __float2bfloat16(acc0[reg]);
            tile[((w * 4 + kgw) * 32 + f1) * 8 + ew] = __float2bfloat16(acc1[reg]);
            s = fmaf(acc0[reg], av[0][reg], s);
            s = fmaf(acc1[reg], av[1][reg], s);
            d = fmaf(acc0[reg], dv[0][reg], d);
            d = fmaf(acc1[reg], dv[1][reg], d);
        }
        s += __shfl_xor(s, 16); s += __shfl_xor(s, 32);
        d += __shfl_xor(d, 16); d += __shfl_xor(d, 32);
        if (l < 16) {
            es[(long)rbh * NN + ncol] = s;
            ed[(long)rbh * NN + ncol] = d;
        }
    }
}

// ---------------------------------------------------------------------------
// Kernel 2: BARRIER-FREE fused masked softmax + MFMA aggregation.
// block = (r, b, 16-row i-tile, j-half); 4 waves = 4 heads, fully
// independent: no LDS tiles, no s_barrier, no manual waitcnt.
// grid = R*B*128*2 = 1536 blocks (XCD swizzled), 24 waves/CU.
// ---------------------------------------------------------------------------
__global__ __launch_bounds__(256, 6) void gat_attn_kernel(
    const unsigned* __restrict__ bm, const float* __restrict__ es,
    const float* __restrict__ ed, const __hip_bfloat16* __restrict__ whT,
    unsigned* __restrict__ num, float* __restrict__ den)
{
    const int lg = ((int)blockIdx.x % 8) * 192 + (int)blockIdx.x / 8;
    const int jh = lg & 1;
    const int it = (lg >> 1) & 127;        // 16-row i-tile
    const int b  = (lg >> 8) & 1;
    const int r  = lg >> 9;
    const int i0 = it << 4;
    const int tid = threadIdx.x;
    const int h = tid >> 6;                // wave = head
    const int l = tid & 63;
    const int row = l & 15;
    const int kg  = l >> 4;

    const int rb  = r * BB + b;
    const int rbh = rb * HH + h;
    const float* edr = ed + (long)rbh * NN;

    // per-wave max of ed over all 2048 j (upper bound; cancels in num/den)
    float mm = -1e30f;
#pragma unroll
    for (int k = 0; k < 8; ++k) {
        float4 v = ((const float4*)edr)[k * 64 + l];
        mm = fmaxf(mm, fmaxf(fmaxf(v.x, v.y), fmaxf(v.z, v.w)));
    }
#pragma unroll
    for (int d = 1; d < 64; d <<= 1) mm = fmaxf(mm, __shfl_xor(mm, d));

    const float esv = es[(long)rbh * NN + i0 + row];   // log2e-scaled
    const float x = esv + mm;
    const float M = fmaxf(x, LEAKY * x);
    const float uA = esv - M;
    const float vA = fmaf(LEAKY, esv, -M);

    f32x4 acc0 = {0,0,0,0}, acc1 = {0,0,0,0}, accD = {0,0,0,0};
    bf16x8 ones;
#pragma unroll
    for (int i = 0; i < 8; ++i) ones[i] = (short)0x3F80;

    const int kk = kg * 2;
    const unsigned* bmb = bm + (long)rb * 64 * 2048 + i0 + row;

#pragma unroll 1
    for (int seg = 0; seg < 8; ++seg) {
        const int S = jh * 8 + seg;
        const __hip_bfloat16* tile = whT + ((long)rbh * 16 + S) * 4096;
        const int wbase = (S >> 1) * 8 + (S & 1);
        unsigned wA[4];
#pragma unroll
        for (int q = 0; q < 4; ++q)
            wA[q] = bmb[(long)(wbase + q * 2) * 2048];
        const float* edseg = edr + S * 128;

#pragma unroll
        for (int jc = 0; jc < 4; ++jc) {
            bf16x8 b0 = *(const bf16x8*)(tile + jc * 1024 + kg * 256 + row * 8);
            bf16x8 b1 = *(const bf16x8*)(tile + jc * 1024 + kg * 256 + 128 + row * 8);
            float4 e0 = *(const float4*)(edseg + jc * 32 + kg * 8);
            float4 e1 = *(const float4*)(edseg + jc * 32 + kg * 8 + 4);

            unsigned uq[4];
#pragma unroll
            for (int q = 0; q < 4; ++q) uq[q] = wA[q] >> (jc * 8 + kk);

            float ev[8];
            ev[0] = e0.x; ev[1] = e0.y; ev[2] = e0.z; ev[3] = e0.w;
            ev[4] = e1.x; ev[5] = e1.y; ev[6] = e1.z; ev[7] = e1.w;

            bf16x8 p;
#pragma unroll
            for (int c = 0; c < 8; ++c) {
                float pa = __builtin_amdgcn_exp2f(
                    fmaxf(uA + ev[c], fmaf(LEAKY, ev[c], vA)));
                const int ma = ((int)(uq[c & 3] << (31 - (c >> 2)))) >> 31;
                pa = __uint_as_float(__float_as_uint(pa) & (unsigned)ma);
                __hip_bfloat16 ha = __float2bfloat16(pa);
                p[c] = __builtin_bit_cast(short, ha);
            }

            __builtin_amdgcn_s_setprio(1);
            acc0 = __builtin_amdgcn_mfma_f32_16x16x32_bf16(p, b0, acc0, 0, 0, 0);
            acc1 = __builtin_amdgcn_mfma_f32_16x16x32_bf16(p, b1, acc1, 0, 0, 0);
            accD = __builtin_amdgcn_mfma_f32_16x16x32_bf16(p, ones, accD, 0, 0, 0);
            __builtin_amdgcn_s_setprio(0);
        }
    }

    // epilogue: packed bf16 numerators + fp32 denominators
    const int fcol = l & 15;
    const int pr = r * 2 + jh;
#pragma unroll
    for (int reg = 0; reg < 4; ++reg) {
        const int orow = (l >> 4) * 4 + reg;
        const long ro = (long)pr * (BB * NN) + (long)b * NN + i0 + orow;
        num[ro * 64 + h * 16 + fcol] =
            (unsigned)bfb(acc0[reg]) | ((unsigned)bfb(acc1[reg]) << 16);
        if (fcol == 0) den[ro * HH + h] = accD[reg];
    }
}

// ---------------------------------------------------------------------------
// Kernel 3: out = LayerNorm(H + mean_r (num_r / den_r)); 2 j-chunks.
// ---------------------------------------------------------------------------
__global__ __launch_bounds__(256) void finalize_kernel(
    const float* __restrict__ H, const unsigned* __restrict__ num,
    const float* __restrict__ den,
    const float* __restrict__ gamma, const float* __restrict__ beta,
    float* __restrict__ out)
{
    const int w = threadIdx.x >> 6;
    const int l = threadIdx.x & 63;
    const long row = (long)blockIdx.x * 4 + w;
    const int hh = l >> 4, cc = l & 15;
    const int c_lo = hh * 32 + cc, c_hi = c_lo + 16;
    const float hx = H[row * DD + c_lo];
    const float hy = H[row * DD + c_hi];

    float ax = 0.f, ay = 0.f;
#pragma unroll
    for (int r = 0; r < RR; ++r) {
        float dsum = 0.f, nx = 0.f, ny = 0.f;
#pragma unroll
        for (int j = 0; j < 2; ++j) {
            const long ro = (long)(r * 2 + j) * (BB * NN) + row;
            dsum += den[ro * HH + hh];
            const unsigned wv = num[ro * 64 + l];
            nx += __uint_as_float(wv << 16);
            ny += __uint_as_float(wv & 0xffff0000u);
        }
        const float inv = (dsum > 0.f) ? 1.0f / dsum : 0.0f;
        ax = fmaf(nx, inv, ax);
        ay = fmaf(ny, inv, ay);
    }
    const float x0 = hx + ax * (1.0f / RR);
    const float x1 = hy + ay * (1.0f / RR);
    float s = x0 + x1, q = x0 * x0 + x1 * x1;
#pragma unroll
    for (int m = 1; m < 64; m <<= 1) {
        s += __shfl_xor(s, m);
        q += __shfl_xor(q, m);
    }
    const float mu  = s * (1.0f / DD);
    const float var = q * (1.0f / DD) - mu * mu;
    const float inv = rsqrtf(var + LN_EPS);
    out[row * DD + c_lo] = (x0 - mu) * inv * gamma[c_lo] + beta[c_lo];
    out[row * DD + c_hi] = (x1 - mu) * inv * gamma[c_hi] + beta[c_hi];
}

// ---------------------------------------------------------------------------
extern "C" void kernel_launch(void* const* d_in, const int* in_sizes, int n_in,
                              void* d_out, int out_size, void* d_ws, size_t ws_size,
                              hipStream_t stream)
{
    const float* H      = (const float*)d_in[0];
    const int*   A      = (const int*)d_in[1];
    const float* W      = (const float*)d_in[2];
    const float* a_src  = (const float*)d_in[3];
    const float* a_dst  = (const float*)d_in[4];
    const float* gamma  = (const float*)d_in[5];
    const float* beta   = (const float*)d_in[6];
    float* out = (float*)d_out;

    // workspace carve (~13.4 MB)
    char* ws = (char*)d_ws;
    unsigned* num = (unsigned*)ws;               ws += (size_t)RR * 2 * BB * NN * 64 * 4;
    float* den = (float*)ws;                     ws += (size_t)RR * 2 * BB * NN * HH * 4;
    float* es  = (float*)ws;                     ws += (size_t)RR * BB * HH * NN * 4;
    float* ed  = (float*)ws;                     ws += (size_t)RR * BB * HH * NN * 4;
    __hip_bfloat16* whT = (__hip_bfloat16*)ws;   ws += (size_t)RR * BB * HH * HD * NN * 2;
    unsigned* bmask = (unsigned*)ws;             ws += (size_t)RR * BB * NN * (NN / 32) * 4;

    prep_kernel<<<768 + 384, 256, 0, stream>>>(
        H, A, W, a_src, a_dst, es, ed, whT, bmask);
    gat_attn_kernel<<<RR * BB * 128 * 2, 256, 0, stream>>>(bmask, es, ed, whT, num, den);
    finalize_kernel<<<BB * NN / 4, 256, 0, stream>>>(H, num, den, gamma, beta, out);
}